// Round 1
// baseline (270.544 us; speedup 1.0000x reference)
//
#include <hip/hip_runtime.h>

// EdgeClassifier: out[e] = W2 . relu(W1 . concat(z_drug[row[e]], z_protein[col[e]]) + b1) + b2
// Layer 1 as bf16 MFMA GEMM: C[64-edge tile x 128 outputs] = Zb[64x256] * W1b^T
// Layer 2 fused in epilogue (fp32).

typedef __attribute__((ext_vector_type(8))) short bhalf8;   // 8 x bf16 (4 VGPRs)
typedef __attribute__((ext_vector_type(4))) float f32x4;

#define TE 64   // edges per tile

__device__ __forceinline__ unsigned bfr(float f) {
    // fp32 -> bf16 bits, round-to-nearest-even
    unsigned u = __builtin_bit_cast(unsigned, f);
    return (u + 0x7fffu + ((u >> 16) & 1u)) >> 16;
}

__device__ __forceinline__ unsigned pk2(float a, float b) {
    return bfr(a) | (bfr(b) << 16);
}

__global__ __launch_bounds__(512, 4) void ec_kernel(
    const float* __restrict__ zd, const float* __restrict__ zp,
    const int* __restrict__ eli, const float* __restrict__ W1,
    const float* __restrict__ b1, const float* __restrict__ W2,
    const float* __restrict__ b2, float* __restrict__ out,
    int E, int nTiles)
{
    // Z tile in bf16, row-major [TE][256], XOR-swizzled: byte ^= (row&7)<<4
    __shared__ __align__(16) short sZ[TE * 256];      // 32 KB
    __shared__ float sPart[8][TE];                    // 2 KB cross-wave partials

    const int tid  = threadIdx.x;
    const int wave = tid >> 6;        // 0..7 -> output col tile = wave*16
    const int lane = tid & 63;
    const int l15  = lane & 15;
    const int lhi  = lane >> 4;       // 0..3

    // --- per-block: this wave's W1 column-tile as bf16 B-fragments in registers ---
    // B-frag lane mapping (16x16x32): lane holds B[k][col] = W1[col][k],
    // col = wave*16 + (l&15), k = ks*32 + (l>>4)*8 + i
    const int ocol = wave * 16 + l15;
    bhalf8 bfrag[8];
    #pragma unroll
    for (int ks = 0; ks < 8; ++ks) {
        const int k0 = ks * 32 + lhi * 8;
        const float4* src = (const float4*)(W1 + ocol * 256 + k0);
        float4 p = src[0], q = src[1];
        bhalf8 f;
        f[0] = (short)bfr(p.x); f[1] = (short)bfr(p.y);
        f[2] = (short)bfr(p.z); f[3] = (short)bfr(p.w);
        f[4] = (short)bfr(q.x); f[5] = (short)bfr(q.y);
        f[6] = (short)bfr(q.z); f[7] = (short)bfr(q.w);
        bfrag[ks] = f;
    }
    const float b1v = b1[ocol];
    const float w2v = W2[ocol];     // W2 shape (1,128) row-major
    const float b2v = b2[0];

    const int slot   = tid >> 5;    // 0..15, each stages 4 edges
    const int lane32 = tid & 31;

    for (int tile = blockIdx.x; tile < nTiles; tile += gridDim.x) {
        const int base = tile * TE;
        __syncthreads();   // sZ / sPart safe to overwrite

        // --- stage: gather 64 edges, convert fp32->bf16 into swizzled LDS ---
        #pragma unroll
        for (int r = 0; r < 4; ++r) {
            const int e  = slot * 4 + r;       // edge within tile
            const int eg = base + e;
            int drow = 0, pcol = 0;
            if (eg < E) { drow = eli[eg]; pcol = eli[E + eg]; }
            float4 v = ((const float4*)(zd + (size_t)drow * 128))[lane32];
            float4 u = ((const float4*)(zp + (size_t)pcol * 128))[lane32];
            int byte0 = e * 512 + lane32 * 8;          // drug half: k = lane32*4
            byte0 ^= (e & 7) << 4;
            uint2 pv; pv.x = pk2(v.x, v.y); pv.y = pk2(v.z, v.w);
            *(uint2*)((char*)sZ + byte0) = pv;
            int byte1 = e * 512 + 256 + lane32 * 8;    // protein half: k = 128 + lane32*4
            byte1 ^= (e & 7) << 4;
            uint2 pu; pu.x = pk2(u.x, u.y); pu.y = pk2(u.z, u.w);
            *(uint2*)((char*)sZ + byte1) = pu;
        }
        __syncthreads();

        // --- MFMA: 4 row-tiles x 8 K-steps ---
        f32x4 acc[4] = {{0.f,0.f,0.f,0.f},{0.f,0.f,0.f,0.f},
                        {0.f,0.f,0.f,0.f},{0.f,0.f,0.f,0.f}};
        #pragma unroll
        for (int ks = 0; ks < 8; ++ks) {
            const int kb = (ks * 32 + lhi * 8) * 2;    // byte offset along K
            #pragma unroll
            for (int rt = 0; rt < 4; ++rt) {
                const int row = rt * 16 + l15;
                int byte = row * 512 + kb;
                byte ^= (row & 7) << 4;
                bhalf8 af = *(const bhalf8*)((const char*)sZ + byte);
                acc[rt] = __builtin_amdgcn_mfma_f32_16x16x32_bf16(af, bfrag[ks], acc[rt], 0, 0, 0);
            }
        }

        // --- epilogue: +b1, relu, *W2, reduce over 128 output cols ---
        // D mapping: row = rt*16 + (l>>4)*4 + i (edge), col = wave*16 + (l&15)
        #pragma unroll
        for (int rt = 0; rt < 4; ++rt) {
            #pragma unroll
            for (int i = 0; i < 4; ++i) {
                float v = acc[rt][i] + b1v;
                v = fmaxf(v, 0.0f) * w2v;
                v += __shfl_xor(v, 1, 64);
                v += __shfl_xor(v, 2, 64);
                v += __shfl_xor(v, 4, 64);
                v += __shfl_xor(v, 8, 64);   // sum over the 16 cols this wave owns
                if (l15 == 0) sPart[wave][rt * 16 + lhi * 4 + i] = v;
            }
        }
        __syncthreads();
        if (tid < TE) {
            const int eg = base + tid;
            if (eg < E) {
                float s = b2v;
                #pragma unroll
                for (int w = 0; w < 8; ++w) s += sPart[w][tid];
                out[eg] = s;
            }
        }
    }
}

extern "C" void kernel_launch(void* const* d_in, const int* in_sizes, int n_in,
                              void* d_out, int out_size, void* d_ws, size_t ws_size,
                              hipStream_t stream) {
    const float* zd = (const float*)d_in[0];
    const float* zp = (const float*)d_in[1];
    const int*   eli = (const int*)d_in[2];
    const float* W1 = (const float*)d_in[3];
    const float* b1 = (const float*)d_in[4];
    const float* W2 = (const float*)d_in[5];
    const float* b2 = (const float*)d_in[6];
    float* out = (float*)d_out;

    const int E = in_sizes[2] / 2;
    const int nTiles = (E + TE - 1) / TE;
    const int nBlocks = 2048;

    hipLaunchKernelGGL(ec_kernel, dim3(nBlocks), dim3(512), 0, stream,
                       zd, zp, eli, W1, b1, W2, b2, out, E, nTiles);
}